// Round 9
// baseline (1404.291 us; speedup 1.0000x reference)
//
#include <hip/hip_runtime.h>
#include <math.h>

// Problem constants
#define B_    256
#define NPTS  1024
#define T_    50

// ---------------------------------------------------------------------------
// ws layout (bytes):
//   [0,       786432)   wp   f32 [64][3][256][4]  packed W_hh (round-7 layout)
//   [786432,  1310720)  henc u32 [256][512]       (f32-bit maxpool via atomicMax)
//   [1310720, 1441792)  ow1d f64 [256][64]
//   [1441792, 1474560)  ow2d f64 [64][64]
//   [1474560, 1477632)  ow3d f64 [64][6]
// ---------------------------------------------------------------------------

__global__ __launch_bounds__(256) void prep_kernel(
    const float* __restrict__ whh, const float* __restrict__ ow1,
    const float* __restrict__ ow2, const float* __restrict__ ow3,
    float* __restrict__ wp, unsigned* __restrict__ henc,
    double* __restrict__ ow1d, double* __restrict__ ow2d,
    double* __restrict__ ow3d) {
  int idx = blockIdx.x * 256 + threadIdx.x;   // grid 768*256 = 196608
  if (idx < 196608) {
    int c = idx & 3;
    int r = idx >> 2;            // (k4*3+j)*256 + t
    int t2 = r & 255;
    int q = r >> 8;              // k4*3 + j
    int j = q % 3;
    int k4 = q / 3;
    wp[idx] = whh[(j * 256 + t2) * 256 + (k4 * 4 + c)];
  }
  if (idx < 131072) henc[idx] = 0u;           // bits 0 == +0.0f; relu>=0 valid
  if (idx < 16384) ow1d[idx] = (double)ow1[idx];
  if (idx < 4096)  ow2d[idx] = (double)ow2[idx];
  if (idx < 384)   ow3d[idx] = (double)ow3[idx];
}

// ---------------------------------------------------------------------------
// Encoder, register-tiled 8x8 GEMM (round-8 was sK$-bound: per-block w3
// footprint 256 KB thrashes the scalar cache every tile). Block = half
// sample, 512 threads = 8 waves. GEMM role: lane = out-group (8 outs,
// coalesced dwordx4 weight loads, 2-KB row per wave per k, L1-reused by
// all 8 waves), wave = point-group (8 pts, broadcast ds_read_b128).
// 64 FMA per 4 mem-instr. Staging: wave = 16-channel slice (uniform w2 ->
// s_load), lane = point. Per-(pt,ch) fma order identical to rounds 3-8
// -> henc bit-identical.
// ---------------------------------------------------------------------------
__global__ __launch_bounds__(512, 4) void enc_kernel(
    const float* __restrict__ data,
    const float* __restrict__ w1, const float* __restrict__ b1,
    const float* __restrict__ w2, const float* __restrict__ b2,
    const float* __restrict__ w3, const float* __restrict__ b3,
    unsigned* __restrict__ henc) {
  __shared__ float h2t[128][72];              // 72: 16B-aligned rows, pad
  __shared__ float pool_l[8][512];
  const int t = threadIdx.x;
  const int b = blockIdx.x >> 1;
  const int half = blockIdx.x & 1;
  const int og = t & 63;                      // GEMM: lane -> outs [8og, 8og+8)
  const int pg = t >> 6;                      // GEMM: wave -> pts  [8pg, 8pg+8)
  const int spt = t & 63;                     // staging: lane -> point
  const int scg = t >> 6;                     // staging: wave -> 16-ch slice

  float m[8];
#pragma unroll
  for (int oo = 0; oo < 8; ++oo) m[oo] = 0.0f;   // relu via max with 0
  const float4 b3a = *(const float4*)(b3 + og * 8);
  const float4 b3b = *(const float4*)(b3 + og * 8 + 4);
  const float* __restrict__ w3l = w3 + og * 8;

#pragma unroll 1
  for (int tile = 0; tile < 8; ++tile) {
    // ---- stage layers 1+2: 64 points x 128 channels ----
    {
      const int ptg = b * NPTS + half * 512 + tile * 64 + spt;
      const float x0 = data[ptg * 3], x1 = data[ptg * 3 + 1], x2 = data[ptg * 3 + 2];
      float a[16];
#pragma unroll
      for (int c = 0; c < 16; ++c) a[c] = b2[scg * 16 + c];    // s_load
#pragma unroll 4
      for (int j = 0; j < 64; ++j) {                           // w1/b1 uniform
        float hj = fmaf(x0, w1[j], fmaf(x1, w1[64 + j], fmaf(x2, w1[128 + j], b1[j])));
        hj = fmaxf(hj, 0.0f);
        const float* __restrict__ w2r = w2 + j * 128 + scg * 16; // s_load x16
#pragma unroll
        for (int c = 0; c < 16; ++c) a[c] = fmaf(hj, w2r[c], a[c]);
      }
#pragma unroll
      for (int c = 0; c < 16; ++c) h2t[scg * 16 + c][spt] = fmaxf(a[c], 0.0f);
    }
    __syncthreads();

    // ---- layer-3 GEMM: 8 outs (lane) x 8 pts (wave), k = 0..127 ----
    float acc[64];
#pragma unroll
    for (int pp2 = 0; pp2 < 8; ++pp2) {
      acc[pp2 * 8 + 0] = b3a.x; acc[pp2 * 8 + 1] = b3a.y;
      acc[pp2 * 8 + 2] = b3a.z; acc[pp2 * 8 + 3] = b3a.w;
      acc[pp2 * 8 + 4] = b3b.x; acc[pp2 * 8 + 5] = b3b.y;
      acc[pp2 * 8 + 6] = b3b.z; acc[pp2 * 8 + 7] = b3b.w;
    }
#pragma unroll 2
    for (int k = 0; k < 128; ++k) {
      const float4 wa = *(const float4*)(w3l + k * 512);       // coalesced
      const float4 wb = *(const float4*)(w3l + k * 512 + 4);
      const float4 pa = *(const float4*)(&h2t[k][pg * 8]);     // broadcast
      const float4 pb = *(const float4*)(&h2t[k][pg * 8 + 4]);
      const float wv8[8] = {wa.x, wa.y, wa.z, wa.w, wb.x, wb.y, wb.z, wb.w};
      const float pv8[8] = {pa.x, pa.y, pa.z, pa.w, pb.x, pb.y, pb.z, pb.w};
#pragma unroll
      for (int pp2 = 0; pp2 < 8; ++pp2)
#pragma unroll
        for (int oo = 0; oo < 8; ++oo)
          acc[pp2 * 8 + oo] = fmaf(pv8[pp2], wv8[oo], acc[pp2 * 8 + oo]);
    }
#pragma unroll
    for (int pp2 = 0; pp2 < 8; ++pp2)
#pragma unroll
      for (int oo = 0; oo < 8; ++oo)
        m[oo] = fmaxf(m[oo], acc[pp2 * 8 + oo]);
    __syncthreads();                                           // h2t reuse guard
  }

  // ---- pool across the 8 point-groups via LDS ----
#pragma unroll
  for (int oo = 0; oo < 8; ++oo) pool_l[pg][og * 8 + oo] = m[oo];
  __syncthreads();
  {
    const int o = t;                                           // 512 threads
    float v = pool_l[0][o];
#pragma unroll
    for (int p2 = 1; p2 < 8; ++p2) v = fmaxf(v, pool_l[p2][o]);
    atomicMax(henc + b * 512 + o, __float_as_uint(v));
  }
}

// ---------------------------------------------------------------------------
// Fast f64 exp (Cody-Waite + degree-13 Taylor, branch-free, ~1 ulp).
// ---------------------------------------------------------------------------
__device__ __forceinline__ double fexp(double x) {
  const double n = rint(x * 1.44269504088896338700e+00);
  const double r = fma(-n, 1.90821492927058770002e-10,
                       fma(-n, 6.93147180369123816490e-01, x));
  double p = 1.0 / 6227020800.0;                 // 1/13!
  p = fma(p, r, 1.0 / 479001600.0);
  p = fma(p, r, 1.0 / 39916800.0);
  p = fma(p, r, 1.0 / 3628800.0);
  p = fma(p, r, 1.0 / 362880.0);
  p = fma(p, r, 1.0 / 40320.0);
  p = fma(p, r, 1.0 / 5040.0);
  p = fma(p, r, 1.0 / 720.0);
  p = fma(p, r, 1.0 / 120.0);
  p = fma(p, r, 1.0 / 24.0);
  p = fma(p, r, 1.0 / 6.0);
  p = fma(p, r, 0.5);
  p = fma(p, r, 1.0);
  p = fma(p, r, 1.0);
  return ldexp(p, (int)n);
}
__device__ __forceinline__ double fsigm(double x) { return 1.0 / (1.0 + fexp(-x)); }
__device__ __forceinline__ double ftanh(double y) {
  const double e = fexp(-2.0 * y);
  return (1.0 - e) / (1.0 + e);
}

// ---------------------------------------------------------------------------
// GRU rollout, f64, grid 128, block = 2 samples x 1024 threads (16 waves).
// t<768 matvec: thread = (c = t&255, third = t>>8), ~21 k4 each -> 3
// waves/SIMD (round 8: 2) for latency hiding; partials pp[third][gate][g,c]
// combined in the gates phase ((q0+q1)+q2, f64-invisible reassoc). Gates on
// t<512 (thread (c,g) owns h[g][c] in a register). t in [768,1024):
// out_mlp (4 waves) overlapped with the 3 matvec chunks. wih transposed in
// LDS ([a][768]: round 8's [o][6] layout was an 8-way bank-conflict read).
// ---------------------------------------------------------------------------
__global__ __launch_bounds__(1024) void gru_kernel(
    const float* __restrict__ henc,     // [256][512] (maxpool bits)
    const float* __restrict__ mw1, const float* __restrict__ mb1,
    const float* __restrict__ mw2, const float* __restrict__ mb2,
    const float* __restrict__ mw3, const float* __restrict__ mb3,
    const float* __restrict__ wih, const float* __restrict__ wp,
    const float* __restrict__ bih, const float* __restrict__ bhh,
    const double* __restrict__ ow1d, const float* __restrict__ ob1,
    const double* __restrict__ ow2d, const float* __restrict__ ob2,
    const double* __restrict__ ow3d, const float* __restrict__ ob3,
    float* __restrict__ dout) {
  __shared__ __align__(16) double h_l[512];   // [g][c]
  __shared__ double pp[3][3][512];            // [third][gate][g*256+c]
  __shared__ double g1_l[512];                // phase 0
  __shared__ double g2_l[256];                // phase 0
  __shared__ double o1p[2][128];              // [q][g*64+j]
  __shared__ double o1_l[128];                // [g*64+j]
  __shared__ double o2_l[128];
  __shared__ double gia_l[12];                // [g][c]
  __shared__ double wihT[6][768];             // transposed W_ih
  __shared__ double bihd[768];

  const int t = threadIdx.x;
  const int s0 = blockIdx.x << 1;

  for (int i = t; i < 4608; i += 1024) {
    const int o = i / 6, a = i - o * 6;
    wihT[a][o] = (double)wih[i];
  }
  if (t < 768) bihd[t] = (double)bih[t];

  // ---- phase 0: gru_h init MLP (512->256->128->256), f64 ----
  if (t < 512) {
    const int o = t & 255, g = t >> 8;                    // g wave-uniform
    const float* __restrict__ hrow = henc + ((s0 + g) << 9);   // uniform
    double a = (double)mb1[o];
#pragma unroll 4
    for (int k = 0; k < 512; ++k)
      a = fma((double)hrow[k], (double)mw1[k * 256 + o], a);
    g1_l[(g << 8) + o] = fmax(a, 0.0);
  }
  __syncthreads();
  if (t < 256) {
    const int o = t & 127, g = t >> 7;
    double a = (double)mb2[o];
#pragma unroll 4
    for (int k = 0; k < 256; ++k) a = fma(g1_l[(g << 8) + k], (double)mw2[k * 128 + o], a);
    g2_l[(g << 7) + o] = fmax(a, 0.0);
  }
  __syncthreads();
  double hreg = 0.0;
  if (t < 512) {
    const int o = t & 255, g = t >> 8;
    double a = (double)mb3[o];
#pragma unroll 4
    for (int k = 0; k < 128; ++k) a = fma(g2_l[(g << 7) + k], (double)mw3[k * 256 + o], a);
    hreg = a;                          // gate thread (c=o, g) owns h[g][c]
    h_l[(g << 8) + o] = a;
  }
  if (t < 12) gia_l[t] = 0.0;
  __syncthreads();

  // ---- matvec thread constants ----
  const int c = t & 255;
  const int third = t >> 8;            // 0..2 matvec, 3 = out_mlp
  const int k4a = (third == 0) ? 0 : (third == 1) ? 22 : 43;
  const int k4b = (third == 0) ? 22 : (third == 1) ? 43 : 64;
  const double br = (third == 0) ? (double)bhh[c] : 0.0;
  const double bz = (third == 0) ? (double)bhh[256 + c] : 0.0;
  const double bn = (third == 0) ? (double)bhh[512 + c] : 0.0;
  const int tb = t - 768;

  double ar0, ar1, az0, az1, an0, an1;

#define MV_K4(k4) {                                                          \
    const int wbase = ((k4) * 768 + c) * 4;                                  \
    const float4 wr = *(const float4*)(wp + wbase);                          \
    const float4 wz = *(const float4*)(wp + wbase + 1024);                   \
    const float4 wn = *(const float4*)(wp + wbase + 2048);                   \
    const double2 ha = *(const double2*)(h_l + ((k4) << 2));                 \
    const double2 hb = *(const double2*)(h_l + ((k4) << 2) + 2);             \
    const double2 hc = *(const double2*)(h_l + 256 + ((k4) << 2));           \
    const double2 hd = *(const double2*)(h_l + 256 + ((k4) << 2) + 2);       \
    ar0 = fma(ha.x, (double)wr.x, ar0); ar0 = fma(ha.y, (double)wr.y, ar0);  \
    ar0 = fma(hb.x, (double)wr.z, ar0); ar0 = fma(hb.y, (double)wr.w, ar0);  \
    az0 = fma(ha.x, (double)wz.x, az0); az0 = fma(ha.y, (double)wz.y, az0);  \
    az0 = fma(hb.x, (double)wz.z, az0); az0 = fma(hb.y, (double)wz.w, az0);  \
    an0 = fma(ha.x, (double)wn.x, an0); an0 = fma(ha.y, (double)wn.y, an0);  \
    an0 = fma(hb.x, (double)wn.z, an0); an0 = fma(hb.y, (double)wn.w, an0);  \
    ar1 = fma(hc.x, (double)wr.x, ar1); ar1 = fma(hc.y, (double)wr.y, ar1);  \
    ar1 = fma(hd.x, (double)wr.z, ar1); ar1 = fma(hd.y, (double)wr.w, ar1);  \
    az1 = fma(hc.x, (double)wz.x, az1); az1 = fma(hc.y, (double)wz.y, az1);  \
    az1 = fma(hd.x, (double)wz.z, az1); az1 = fma(hd.y, (double)wz.w, az1);  \
    an1 = fma(hc.x, (double)wn.x, an1); an1 = fma(hc.y, (double)wn.y, an1);  \
    an1 = fma(hd.x, (double)wn.z, an1); an1 = fma(hd.y, (double)wn.w, an1);  \
  }
#define MV_RESET() { ar0 = br; ar1 = br; az0 = bz; az1 = bz; an0 = bn; an1 = bn; }
#define MV_PUBLISH() {                                                       \
    pp[third][0][c] = ar0; pp[third][0][256 + c] = ar1;                      \
    pp[third][1][c] = az0; pp[third][1][256 + c] = az1;                      \
    pp[third][2][c] = an0; pp[third][2][256 + c] = an1;                      \
  }

  // ---- prologue: partials of comb(h0) ----
  if (t < 768) {
    MV_RESET();
#pragma unroll 2
    for (int k4 = k4a; k4 < k4b; ++k4) MV_K4(k4);
    MV_PUBLISH();
  }
  __syncthreads();

  for (int step = 0; step < T_; ++step) {
    // ---- gates + h update (t<512, thread = (c, g)) ----
    if (t < 512) {
      const int g = t >> 8;
      const int gg = (g << 8) + c;
      const double cr = (pp[0][0][gg] + pp[1][0][gg]) + pp[2][0][gg];
      const double cz = (pp[0][1][gg] + pp[1][1][gg]) + pp[2][1][gg];
      const double cn = (pp[0][2][gg] + pp[1][2][gg]) + pp[2][2][gg];
      double gr = bihd[c], gz = bihd[256 + c], gn = bihd[512 + c];
#pragma unroll
      for (int a = 0; a < 6; ++a) {
        const double xa = gia_l[g * 6 + a];
        gr = fma(wihT[a][c], xa, gr);
        gz = fma(wihT[a][256 + c], xa, gz);
        gn = fma(wihT[a][512 + c], xa, gn);
      }
      const double rv = fsigm(cr + gr);
      const double zv = fsigm(cz + gz);
      const double nv = ftanh(fma(rv, cn, gn));
      hreg = fma(zv, hreg - nv, nv);
      h_l[gg] = hreg;
    }
    __syncthreads();                    // h published

    // ---- c1: matvec part 1 || out_mlp L1 (k-split x2, sample-split) ----
    if (t < 768) {
      MV_RESET();
#pragma unroll 2
      for (int k4 = k4a; k4 < k4a + 7; ++k4) MV_K4(k4);
    } else {
      const int j = tb & 63, g = (tb >> 6) & 1, q = tb >> 7;
      double a = (q == 0) ? (double)ob1[j] : 0.0;
      const int k0 = q << 7;
#pragma unroll 4
      for (int k = k0; k < k0 + 128; ++k)
        a = fma(h_l[(g << 8) + k], ow1d[k * 64 + j], a);   // h broadcast
      o1p[q][(g << 6) + j] = a;
    }
    __syncthreads();

    // ---- c2: matvec part 2 || combine o1 + L2 ----
    if (t < 768) {
#pragma unroll 2
      for (int k4 = k4a + 7; k4 < k4a + 14; ++k4) MV_K4(k4);
    } else if (tb < 128) {
      const int j = tb & 63, g = tb >> 6;                  // one wave per g
      o1_l[(g << 6) + j] = fmax(o1p[0][(g << 6) + j] + o1p[1][(g << 6) + j], 0.0);
      __builtin_amdgcn_wave_barrier();                     // wave-local LDS
      double a = (double)ob2[j];
#pragma unroll 4
      for (int k = 0; k < 64; ++k)
        a = fma(o1_l[(g << 6) + k], ow2d[k * 64 + j], a);
      o2_l[(g << 6) + j] = fmax(a, 0.0);
    }
    __syncthreads();

    // ---- c3: matvec part 3 + publish || L3 + gia + stores ----
    if (t < 768) {
#pragma unroll 2
      for (int k4 = k4a + 14; k4 < k4b; ++k4) MV_K4(k4);
      MV_PUBLISH();
    } else if (tb < 12) {
      const int g = tb / 6, cc = tb - g * 6;
      double a = (double)ob3[cc];
#pragma unroll 4
      for (int k = 0; k < 64; ++k) a = fma(o2_l[(g << 6) + k], ow3d[k * 6 + cc], a);
      const double gi_new = gia_l[g * 6 + cc] + a;
      gia_l[g * 6 + cc] = gi_new;
      const int s = s0 + g;
      dout[s * 300 + step * 6 + cc] = (float)a;              // dws
      dout[76800 + s * 300 + step * 6 + cc] = (float)gi_new; // ws
    }
    __syncthreads();                    // pp + gia ready for next gates
  }
#undef MV_K4
#undef MV_RESET
#undef MV_PUBLISH
}

extern "C" void kernel_launch(void* const* d_in, const int* in_sizes, int n_in,
                              void* d_out, int out_size, void* d_ws, size_t ws_size,
                              hipStream_t stream) {
  const float* data = (const float*)d_in[0];
  // d_in[1] = horizon (always 50)
  const float* ew1 = (const float*)d_in[2];
  const float* eb1 = (const float*)d_in[3];
  const float* ew2 = (const float*)d_in[4];
  const float* eb2 = (const float*)d_in[5];
  const float* ew3 = (const float*)d_in[6];
  const float* eb3 = (const float*)d_in[7];
  const float* mw1 = (const float*)d_in[8];
  const float* mb1 = (const float*)d_in[9];
  const float* mw2 = (const float*)d_in[10];
  const float* mb2 = (const float*)d_in[11];
  const float* mw3 = (const float*)d_in[12];
  const float* mb3 = (const float*)d_in[13];
  const float* wih = (const float*)d_in[14];
  const float* whh = (const float*)d_in[15];
  const float* bih = (const float*)d_in[16];
  const float* bhh = (const float*)d_in[17];
  const float* ow1 = (const float*)d_in[18];
  const float* ob1 = (const float*)d_in[19];
  const float* ow2 = (const float*)d_in[20];
  const float* ob2 = (const float*)d_in[21];
  const float* ow3 = (const float*)d_in[22];
  const float* ob3 = (const float*)d_in[23];
  float* out = (float*)d_out;

  char* ws = (char*)d_ws;
  float*    wp   = (float*)(ws);                 // 786432 B
  unsigned* henc = (unsigned*)(ws + 786432);     // 524288 B
  double*   ow1d = (double*)(ws + 1310720);      // 131072 B
  double*   ow2d = (double*)(ws + 1441792);      // 32768 B
  double*   ow3d = (double*)(ws + 1474560);      // 3072 B -> end 1477632

  prep_kernel<<<768, 256, 0, stream>>>(whh, ow1, ow2, ow3, wp, henc,
                                       ow1d, ow2d, ow3d);
  enc_kernel<<<512, 512, 0, stream>>>(data, ew1, eb1, ew2, eb2, ew3, eb3, henc);
  gru_kernel<<<128, 1024, 0, stream>>>((const float*)henc,
                                       mw1, mb1, mw2, mb2, mw3, mb3,
                                       wih, wp, bih, bhh,
                                       ow1d, ob1, ow2d, ob2, ow3d, ob3,
                                       out);
}

// Round 10
// 1362.900 us; speedup vs baseline: 1.0304x; 1.0304x over previous
//
#include <hip/hip_runtime.h>
#include <math.h>

// Problem constants
#define B_    256
#define NPTS  1024
#define T_    50

// ---------------------------------------------------------------------------
// ws layout (bytes):
//   [0,       786432)   wp   f32 [64][3][256][4]  packed W_hh:
//                       wp[((k4*3+j)*256+c)*4+cc] = whh[(j*256+c)*256 + k4*4+cc]
//   [786432,  1310720)  henc u32 [256][512]       (f32-bit maxpool via atomicMax)
// ---------------------------------------------------------------------------

__global__ __launch_bounds__(256) void prep_kernel(const float* __restrict__ whh,
                                                   float* __restrict__ wp,
                                                   unsigned* __restrict__ henc) {
  int idx = blockIdx.x * 256 + threadIdx.x;   // grid 768*256 = 196608
  if (idx < 196608) {
    int c = idx & 3;
    int r = idx >> 2;            // (k4*3+j)*256 + t
    int t2 = r & 255;
    int q = r >> 8;              // k4*3 + j
    int j = q % 3;
    int k4 = q / 3;
    wp[idx] = whh[(j * 256 + t2) * 256 + (k4 * 4 + c)];
  }
  if (idx < 131072) henc[idx] = 0u;           // bits 0 == +0.0f; relu>=0 valid
}

// ---------------------------------------------------------------------------
// Encoder, register-tiled 8x8 GEMM. Fix vs round 9: w2 staged into LDS ONCE
// per block (rounds 5-9 read the 32-KB w2 through the scalar path every
// tile -> sK$ miss per j-iteration dominated the staging phase). Pool via
// LDS atomicMax (2 KB) instead of pool_l[8][512] (16 KB) -> 71.6 KB LDS
// keeps 2 blocks/CU. GEMM fma order identical to rounds 3-9 -> henc
// bit-identical.
// ---------------------------------------------------------------------------
__global__ __launch_bounds__(512, 4) void enc_kernel(
    const float* __restrict__ data,
    const float* __restrict__ w1, const float* __restrict__ b1,
    const float* __restrict__ w2, const float* __restrict__ b2,
    const float* __restrict__ w3, const float* __restrict__ b3,
    unsigned* __restrict__ henc) {
  __shared__ float w2_l[8192];                // 32 KB, loaded once
  __shared__ float h2t[128][72];              // 36 KB (72: 16B-aligned rows)
  __shared__ unsigned pool_l[512];            // 2 KB, u32-bit maxpool
  const int t = threadIdx.x;
  const int b = blockIdx.x >> 1;
  const int half = blockIdx.x & 1;
  const int og = t & 63;                      // GEMM: lane -> outs [8og, 8og+8)
  const int pg = t >> 6;                      // GEMM: wave -> pts  [8pg, 8pg+8)
  const int spt = t & 63;                     // staging: lane -> point
  const int scg = t >> 6;                     // staging: wave -> 16-ch slice

  for (int i = t; i < 8192; i += 512) w2_l[i] = w2[i];    // coalesced, once
  pool_l[t] = 0u;                                         // t < 512
  __syncthreads();

  float m[8];
#pragma unroll
  for (int oo = 0; oo < 8; ++oo) m[oo] = 0.0f;   // relu via max with 0
  const float4 b3a = *(const float4*)(b3 + og * 8);
  const float4 b3b = *(const float4*)(b3 + og * 8 + 4);
  const float* __restrict__ w3l = w3 + og * 8;

#pragma unroll 1
  for (int tile = 0; tile < 8; ++tile) {
    // ---- stage layers 1+2: 64 points x 128 channels ----
    {
      const int ptg = b * NPTS + half * 512 + tile * 64 + spt;
      const float x0 = data[ptg * 3], x1 = data[ptg * 3 + 1], x2 = data[ptg * 3 + 2];
      float a[16];
#pragma unroll
      for (int c = 0; c < 16; ++c) a[c] = b2[scg * 16 + c];    // s_load (512 B)
#pragma unroll 4
      for (int j = 0; j < 64; ++j) {                           // w1/b1: 1 KB sK$
        float hj = fmaf(x0, w1[j], fmaf(x1, w1[64 + j], fmaf(x2, w1[128 + j], b1[j])));
        hj = fmaxf(hj, 0.0f);
        const float* __restrict__ w2r = w2_l + j * 128 + scg * 16; // LDS broadcast
#pragma unroll
        for (int c = 0; c < 16; ++c) a[c] = fmaf(hj, w2r[c], a[c]);
      }
#pragma unroll
      for (int c = 0; c < 16; ++c) h2t[scg * 16 + c][spt] = fmaxf(a[c], 0.0f);
    }
    __syncthreads();

    // ---- layer-3 GEMM: 8 outs (lane) x 8 pts (wave), k = 0..127 ----
    float acc[64];
#pragma unroll
    for (int pp2 = 0; pp2 < 8; ++pp2) {
      acc[pp2 * 8 + 0] = b3a.x; acc[pp2 * 8 + 1] = b3a.y;
      acc[pp2 * 8 + 2] = b3a.z; acc[pp2 * 8 + 3] = b3a.w;
      acc[pp2 * 8 + 4] = b3b.x; acc[pp2 * 8 + 5] = b3b.y;
      acc[pp2 * 8 + 6] = b3b.z; acc[pp2 * 8 + 7] = b3b.w;
    }
#pragma unroll 2
    for (int k = 0; k < 128; ++k) {
      const float4 wa = *(const float4*)(w3l + k * 512);       // coalesced
      const float4 wb = *(const float4*)(w3l + k * 512 + 4);
      const float4 pa = *(const float4*)(&h2t[k][pg * 8]);     // broadcast
      const float4 pb = *(const float4*)(&h2t[k][pg * 8 + 4]);
      const float wv8[8] = {wa.x, wa.y, wa.z, wa.w, wb.x, wb.y, wb.z, wb.w};
      const float pv8[8] = {pa.x, pa.y, pa.z, pa.w, pb.x, pb.y, pb.z, pb.w};
#pragma unroll
      for (int pp2 = 0; pp2 < 8; ++pp2)
#pragma unroll
        for (int oo = 0; oo < 8; ++oo)
          acc[pp2 * 8 + oo] = fmaf(pv8[pp2], wv8[oo], acc[pp2 * 8 + oo]);
    }
#pragma unroll
    for (int pp2 = 0; pp2 < 8; ++pp2)
#pragma unroll
      for (int oo = 0; oo < 8; ++oo)
        m[oo] = fmaxf(m[oo], acc[pp2 * 8 + oo]);
    __syncthreads();                                           // h2t reuse guard
  }

  // ---- pool across the 8 point-groups via LDS atomicMax (bits monotone) --
#pragma unroll
  for (int oo = 0; oo < 8; ++oo)
    atomicMax(&pool_l[og * 8 + oo], __float_as_uint(m[oo]));
  __syncthreads();
  atomicMax(henc + b * 512 + t, pool_l[t]);                    // t < 512
}

// ---------------------------------------------------------------------------
// Fast f64 exp (Cody-Waite + degree-13 Taylor, branch-free, ~1 ulp).
// ---------------------------------------------------------------------------
__device__ __forceinline__ double fexp(double x) {
  const double n = rint(x * 1.44269504088896338700e+00);
  const double r = fma(-n, 1.90821492927058770002e-10,
                       fma(-n, 6.93147180369123816490e-01, x));
  double p = 1.0 / 6227020800.0;                 // 1/13!
  p = fma(p, r, 1.0 / 479001600.0);
  p = fma(p, r, 1.0 / 39916800.0);
  p = fma(p, r, 1.0 / 3628800.0);
  p = fma(p, r, 1.0 / 362880.0);
  p = fma(p, r, 1.0 / 40320.0);
  p = fma(p, r, 1.0 / 5040.0);
  p = fma(p, r, 1.0 / 720.0);
  p = fma(p, r, 1.0 / 120.0);
  p = fma(p, r, 1.0 / 24.0);
  p = fma(p, r, 1.0 / 6.0);
  p = fma(p, r, 0.5);
  p = fma(p, r, 1.0);
  p = fma(p, r, 1.0);
  return ldexp(p, (int)n);
}
__device__ __forceinline__ double fsigm(double x) { return 1.0 / (1.0 + fexp(-x)); }
__device__ __forceinline__ double ftanh(double y) {
  const double e = fexp(-2.0 * y);
  return (1.0 - e) / (1.0 + e);
}

// ---------------------------------------------------------------------------
// GRU rollout, f64, grid 128, block = 2 samples x 1024 threads. TWO barriers
// per step (round 9: four):
//   A: gates (t<512, thread (c,g)): comb from pp partials, fused gi 6-dot,
//      fast-exp gates, h update -> h_l.
//   B: matvec (t<768, 3-way k-split, publish pp) || FULL out_mlp on one wave
//      per sample (waves 12-13: L1->L2->L3->gia->stores, wave-local LDS
//      sync; DS is in-order per wave). gia double-buffered by step parity
//      so B's writer never races A's readers.
// __launch_bounds__(1024,4) -> 128 VGPR (round 9's 64-VGPR cap allowed only
// ~4 outstanding matvec loads -> L2-latency-bound). out_mlp reads raw f32
// ow* with exact cvt (same values as the old f64 copies).
// ---------------------------------------------------------------------------
__global__ __launch_bounds__(1024, 4) void gru_kernel(
    const float* __restrict__ henc,     // [256][512] (maxpool bits)
    const float* __restrict__ mw1, const float* __restrict__ mb1,
    const float* __restrict__ mw2, const float* __restrict__ mb2,
    const float* __restrict__ mw3, const float* __restrict__ mb3,
    const float* __restrict__ wih, const float* __restrict__ wp,
    const float* __restrict__ bih, const float* __restrict__ bhh,
    const float* __restrict__ ow1, const float* __restrict__ ob1,
    const float* __restrict__ ow2, const float* __restrict__ ob2,
    const float* __restrict__ ow3, const float* __restrict__ ob3,
    float* __restrict__ dout) {
  __shared__ __align__(16) double h_l[512];   // [g][c]
  __shared__ double pp[3][3][512];            // [third][gate][g*256+c]
  __shared__ double g1_l[512];                // phase 0
  __shared__ double g2_l[256];                // phase 0
  __shared__ double o1_l[2][64];              // [g][j]
  __shared__ double o2_l[2][64];
  __shared__ double giab[2][12];              // step-parity double buffer
  __shared__ double wihT[6][768];             // transposed W_ih
  __shared__ double bihd[768];

  const int t = threadIdx.x;
  const int s0 = blockIdx.x << 1;

  for (int i = t; i < 4608; i += 1024) {
    const int o = i / 6, a = i - o * 6;
    wihT[a][o] = (double)wih[i];
  }
  if (t < 768) bihd[t] = (double)bih[t];

  // ---- phase 0: gru_h init MLP (512->256->128->256), f64 ----
  if (t < 512) {
    const int o = t & 255, g = t >> 8;                    // g wave-uniform
    const float* __restrict__ hrow = henc + ((s0 + g) << 9);   // uniform
    double a = (double)mb1[o];
#pragma unroll 4
    for (int k = 0; k < 512; ++k)
      a = fma((double)hrow[k], (double)mw1[k * 256 + o], a);
    g1_l[(g << 8) + o] = fmax(a, 0.0);
  }
  __syncthreads();
  if (t < 256) {
    const int o = t & 127, g = t >> 7;
    double a = (double)mb2[o];
#pragma unroll 4
    for (int k = 0; k < 256; ++k) a = fma(g1_l[(g << 8) + k], (double)mw2[k * 128 + o], a);
    g2_l[(g << 7) + o] = fmax(a, 0.0);
  }
  __syncthreads();
  double hreg = 0.0;
  if (t < 512) {
    const int o = t & 255, g = t >> 8;
    double a = (double)mb3[o];
#pragma unroll 4
    for (int k = 0; k < 128; ++k) a = fma(g2_l[(g << 7) + k], (double)mw3[k * 256 + o], a);
    hreg = a;                          // gate thread (c=o, g) owns h[g][c]
    h_l[(g << 8) + o] = a;
  }
  if (t < 12) giab[0][t] = 0.0;
  __syncthreads();

  // ---- matvec thread constants ----
  const int c = t & 255;
  const int third = t >> 8;            // 0..2 matvec; 3 = out_mlp/idle
  const int k4a = (third == 0) ? 0 : (third == 1) ? 22 : 43;
  const int k4b = (third == 0) ? 22 : (third == 1) ? 43 : 64;
  const double br = (third == 0) ? (double)bhh[c] : 0.0;
  const double bz = (third == 0) ? (double)bhh[256 + c] : 0.0;
  const double bn = (third == 0) ? (double)bhh[512 + c] : 0.0;

  double ar0, ar1, az0, az1, an0, an1;

#define MV_K4(k4) {                                                          \
    const int wbase = ((k4) * 768 + c) * 4;                                  \
    const float4 wr = *(const float4*)(wp + wbase);                          \
    const float4 wz = *(const float4*)(wp + wbase + 1024);                   \
    const float4 wn = *(const float4*)(wp + wbase + 2048);                   \
    const double2 ha = *(const double2*)(h_l + ((k4) << 2));                 \
    const double2 hb = *(const double2*)(h_l + ((k4) << 2) + 2);             \
    const double2 hc = *(const double2*)(h_l + 256 + ((k4) << 2));           \
    const double2 hd = *(const double2*)(h_l + 256 + ((k4) << 2) + 2);       \
    ar0 = fma(ha.x, (double)wr.x, ar0); ar0 = fma(ha.y, (double)wr.y, ar0);  \
    ar0 = fma(hb.x, (double)wr.z, ar0); ar0 = fma(hb.y, (double)wr.w, ar0);  \
    az0 = fma(ha.x, (double)wz.x, az0); az0 = fma(ha.y, (double)wz.y, az0);  \
    az0 = fma(hb.x, (double)wz.z, az0); az0 = fma(hb.y, (double)wz.w, az0);  \
    an0 = fma(ha.x, (double)wn.x, an0); an0 = fma(ha.y, (double)wn.y, an0);  \
    an0 = fma(hb.x, (double)wn.z, an0); an0 = fma(hb.y, (double)wn.w, an0);  \
    ar1 = fma(hc.x, (double)wr.x, ar1); ar1 = fma(hc.y, (double)wr.y, ar1);  \
    ar1 = fma(hd.x, (double)wr.z, ar1); ar1 = fma(hd.y, (double)wr.w, ar1);  \
    az1 = fma(hc.x, (double)wz.x, az1); az1 = fma(hc.y, (double)wz.y, az1);  \
    az1 = fma(hd.x, (double)wz.z, az1); az1 = fma(hd.y, (double)wz.w, az1);  \
    an1 = fma(hc.x, (double)wn.x, an1); an1 = fma(hc.y, (double)wn.y, an1);  \
    an1 = fma(hd.x, (double)wn.z, an1); an1 = fma(hd.y, (double)wn.w, an1);  \
  }
#define MV_RESET() { ar0 = br; ar1 = br; az0 = bz; az1 = bz; an0 = bn; an1 = bn; }
#define MV_PUBLISH() {                                                       \
    pp[third][0][c] = ar0; pp[third][0][256 + c] = ar1;                      \
    pp[third][1][c] = az0; pp[third][1][256 + c] = az1;                      \
    pp[third][2][c] = an0; pp[third][2][256 + c] = an1;                      \
  }

  // ---- prologue: pp = partials of Whh @ h_init ----
  if (t < 768) {
    MV_RESET();
#pragma unroll 2
    for (int k4 = k4a; k4 < k4b; ++k4) MV_K4(k4);
    MV_PUBLISH();
  }
  __syncthreads();

  for (int step = 0; step < T_; ++step) {
    // ---- A: gates + h update (t<512, thread = (c, g)) ----
    if (t < 512) {
      const int g = third;             // 0 or 1
      const int gg = (g << 8) + c;
      const double cr = (pp[0][0][gg] + pp[1][0][gg]) + pp[2][0][gg];
      const double cz = (pp[0][1][gg] + pp[1][1][gg]) + pp[2][1][gg];
      const double cn = (pp[0][2][gg] + pp[1][2][gg]) + pp[2][2][gg];
      double gr = bihd[c], gz = bihd[256 + c], gn = bihd[512 + c];
#pragma unroll
      for (int a = 0; a < 6; ++a) {
        const double xa = giab[step & 1][g * 6 + a];
        gr = fma(wihT[a][c], xa, gr);
        gz = fma(wihT[a][256 + c], xa, gz);
        gn = fma(wihT[a][512 + c], xa, gn);
      }
      const double rv = fsigm(cr + gr);
      const double zv = fsigm(cz + gz);
      const double nv = ftanh(fma(rv, cn, gn));
      hreg = fma(zv, hreg - nv, nv);
      h_l[gg] = hreg;
    }
    __syncthreads();                    // h published

    // ---- B: matvec (t<768) || full out_mlp (waves 12-13) ----
    if (t < 768) {
      MV_RESET();
#pragma unroll 2
      for (int k4 = k4a; k4 < k4b; ++k4) MV_K4(k4);
      MV_PUBLISH();
    } else if (t < 896) {
      const int g = (t >= 832) ? 1 : 0;  // wave 12 -> g=0, wave 13 -> g=1
      const int j = (t - 768) & 63;
      // L1: 256 -> 64
      double a = (double)ob1[j];
#pragma unroll 4
      for (int k = 0; k < 256; ++k)
        a = fma(h_l[(g << 8) + k], (double)ow1[k * 64 + j], a);  // h broadcast
      o1_l[g][j] = fmax(a, 0.0);
      asm volatile("s_waitcnt lgkmcnt(0)" ::: "memory");
      __builtin_amdgcn_wave_barrier();
      // L2: 64 -> 64
      double bacc = (double)ob2[j];
#pragma unroll 4
      for (int k = 0; k < 64; ++k)
        bacc = fma(o1_l[g][k], (double)ow2[k * 64 + j], bacc);
      o2_l[g][j] = fmax(bacc, 0.0);
      asm volatile("s_waitcnt lgkmcnt(0)" ::: "memory");
      __builtin_amdgcn_wave_barrier();
      // L3: 64 -> 6, gia feedback (double-buffered), output stores
      if (j < 6) {
        double d = (double)ob3[j];
#pragma unroll 4
        for (int k = 0; k < 64; ++k) d = fma(o2_l[g][k], (double)ow3[k * 6 + j], d);
        const double gi_new = giab[step & 1][g * 6 + j] + d;
        giab[(step + 1) & 1][g * 6 + j] = gi_new;
        const int s = s0 + g;
        dout[s * 300 + step * 6 + j] = (float)d;              // dws
        dout[76800 + s * 300 + step * 6 + j] = (float)gi_new; // ws
      }
    }
    __syncthreads();                    // pp + gia(parity) ready
  }
#undef MV_K4
#undef MV_RESET
#undef MV_PUBLISH
}

extern "C" void kernel_launch(void* const* d_in, const int* in_sizes, int n_in,
                              void* d_out, int out_size, void* d_ws, size_t ws_size,
                              hipStream_t stream) {
  const float* data = (const float*)d_in[0];
  // d_in[1] = horizon (always 50)
  const float* ew1 = (const float*)d_in[2];
  const float* eb1 = (const float*)d_in[3];
  const float* ew2 = (const float*)d_in[4];
  const float* eb2 = (const float*)d_in[5];
  const float* ew3 = (const float*)d_in[6];
  const float* eb3 = (const float*)d_in[7];
  const float* mw1 = (const float*)d_in[8];
  const float* mb1 = (const float*)d_in[9];
  const float* mw2 = (const float*)d_in[10];
  const float* mb2 = (const float*)d_in[11];
  const float* mw3 = (const float*)d_in[12];
  const float* mb3 = (const float*)d_in[13];
  const float* wih = (const float*)d_in[14];
  const float* whh = (const float*)d_in[15];
  const float* bih = (const float*)d_in[16];
  const float* bhh = (const float*)d_in[17];
  const float* ow1 = (const float*)d_in[18];
  const float* ob1 = (const float*)d_in[19];
  const float* ow2 = (const float*)d_in[20];
  const float* ob2 = (const float*)d_in[21];
  const float* ow3 = (const float*)d_in[22];
  const float* ob3 = (const float*)d_in[23];
  float* out = (float*)d_out;

  char* ws = (char*)d_ws;
  float*    wp   = (float*)(ws);                 // 786432 B
  unsigned* henc = (unsigned*)(ws + 786432);     // 524288 B -> end 1310720

  prep_kernel<<<768, 256, 0, stream>>>(whh, wp, henc);
  enc_kernel<<<512, 512, 0, stream>>>(data, ew1, eb1, ew2, eb2, ew3, eb3, henc);
  gru_kernel<<<128, 1024, 0, stream>>>((const float*)henc,
                                       mw1, mb1, mw2, mb2, mw3, mb3,
                                       wih, wp, bih, bhh,
                                       ow1, ob1, ow2, ob2, ow3, ob3,
                                       out);
}